// Round 8
// baseline (252.515 us; speedup 1.0000x reference)
//
#include <hip/hip_runtime.h>
#include <cstdint>

#define B_  2
#define L_  2048
#define D_  1024
#define H_  16
#define HD_ 64
#define M_  (B_*L_)   // 4096

#define MD  4194304u   // M_*D_
#define DD  1048576u   // D_*D_

// workspace layout (element offsets, unsigned short)
#define OFF_XQB  0u
#define OFF_XKB  (MD)
#define OFF_XVB  (2u*MD)
#define OFF_WQT  (3u*MD)
#define OFF_WKT  (3u*MD + DD)
#define OFF_WVT  (3u*MD + 2u*DD)
#define OFF_GWB  (3u*MD + 3u*DD)
#define OFF_OWB  (3u*MD + 4u*DD)
#define OFF_GATE (3u*MD + 5u*DD)
#define OFF_QB2  (OFF_GATE + MD)
#define OFF_KB2  (OFF_QB2 + MD)
#define OFF_VTG  (OFF_KB2 + MD)
#define OFF_ABUF (OFF_VTG + MD)
#define OFF_F32  (OFF_ABUF + MD)   // float region: ctq|stq|ctk|stk (65536 each)

typedef __attribute__((ext_vector_type(8))) short bf16x8;
typedef __attribute__((ext_vector_type(4))) short s16x4;
typedef __attribute__((ext_vector_type(4))) float f32x4;

__device__ __forceinline__ unsigned short f2b(float x){
  union { float f; unsigned u; } a; a.f = x;
  unsigned r = a.u + 0x7FFFu + ((a.u >> 16) & 1u);
  return (unsigned short)(r >> 16);
}
__device__ __forceinline__ float b2f(unsigned short u){
  union { unsigned u; float f; } a; a.u = ((unsigned)u) << 16; return a.f;
}

// ---------------------------------------------------------------------------
// merged prep: [0,14336) cast; [14336,17408) weight transpose; [17408,17664) xpos
// ---------------------------------------------------------------------------
__global__ __launch_bounds__(256) void prep_kernel(
    const float* __restrict__ q, const float* __restrict__ k,
    const float* __restrict__ v, const float* __restrict__ gw,
    const float* __restrict__ ow, const float* __restrict__ WQ,
    const float* __restrict__ WK, const float* __restrict__ WV,
    unsigned short* __restrict__ ws)
{
  __shared__ float t[32][33];
  const int bx = blockIdx.x, tid = threadIdx.x;
  if (bx < 14336) {
    size_t i = ((size_t)bx * 256 + tid) * 4;
    const float* src; unsigned short* dst;
    if (i < MD)            { src = q  + i;              dst = ws + OFF_XQB + i; }
    else if (i < 2u*MD)    { src = k  + (i - MD);       dst = ws + OFF_XKB + (i - MD); }
    else if (i < 3u*MD)    { src = v  + (i - 2u*MD);    dst = ws + OFF_XVB + (i - 2u*MD); }
    else if (i < 3u*MD+DD) { src = gw + (i - 3u*MD);    dst = ws + OFF_GWB + (i - 3u*MD); }
    else                   { src = ow + (i - 3u*MD-DD); dst = ws + OFF_OWB + (i - 3u*MD - DD); }
    float4 vv = *(const float4*)src;
    ushort4 o; o.x = f2b(vv.x); o.y = f2b(vv.y); o.z = f2b(vv.z); o.w = f2b(vv.w);
    *(ushort4*)dst = o;
  } else if (bx < 17408) {
    const int tb = bx - 14336;
    const int w = tb >> 10;
    const int tb2 = tb & 1023;
    const int h = tb2 >> 6, tt = tb2 & 63;
    const int e0 = (tt & 1) * 32, d0 = (tt >> 1) * 32;
    const float* in = (w == 0) ? WQ : (w == 1) ? WK : WV;
    unsigned short* out = ws + ((w == 0) ? OFF_WQT : (w == 1) ? OFF_WKT : OFF_WVT);
    const int x = tid & 31, y0 = tid >> 5;
    for (int yy = y0; yy < 32; yy += 8)
      t[yy][x] = in[((size_t)h * D_ + d0 + yy) * HD_ + e0 + x];
    __syncthreads();
    for (int yy = y0; yy < 32; yy += 8)
      out[((size_t)h * HD_ + e0 + yy) * D_ + d0 + x] = f2b(t[x][yy]);
  } else {
    float* fb = (float*)(ws + OFF_F32);
    const int idx = (bx - 17408) * 256 + tid;
    const int l = idx >> 5, i = idx & 31;
    const float base = (2.0f * (float)i + 0.4f * (float)HD_) / (1.4f * (float)HD_);
    const float p = (float)(l - L_ / 2) * (1.0f / 512.0f);
    const float sc = exp2f(p * log2f(base));
    const float invf = exp2f(-(float)i * (13.287712379549449f / 32.0f));
    float s, c; sincosf((float)l * invf, &s, &c);
    fb[          l * 32 + i] = c * sc;
    fb[ 65536 +  l * 32 + i] = s * sc;
    const float is = 1.0f / sc;
    fb[131072 +  l * 32 + i] = c * is;
    fb[196608 +  l * 32 + i] = s * is;
  }
}

// ---------------------------------------------------------------------------
// GEMM body: 128x128 tile, K=1024, BK=64, bf16 MFMA, XOR-chunk swizzle.
// 4 waves: wm=wave&1 (64-row M half), wn=wave>>1 (64-col N half); acc 4x4.
// As/Bs 16 KB each (128 rows x 128 B).
// modes: 0 plain->bf16; 1/2 xpos->bf16; 3 silu+bias->bf16; 4 +bias->fp32
// ---------------------------------------------------------------------------
__device__ __forceinline__ void gemm_body(
    const unsigned short* __restrict__ A, const unsigned short* __restrict__ Bt,
    float* __restrict__ outF, unsigned short* __restrict__ outB,
    const float* __restrict__ ct, const float* __restrict__ st,
    const float* __restrict__ bias, int mode, int ldc, int M0, int N0,
    char* As, char* Bs)
{
  const int tid = threadIdx.x;
  const int wave = tid >> 6, lane = tid & 63;
  const int wm = wave & 1, wn = wave >> 1;
  const int mlane = lane & 15, kgrp = lane >> 4;
  const int rl = lane >> 3, csel = lane & 7;
  const char* Ab = (const char*)A;
  const char* Bb = (const char*)Bt;

  f32x4 acc[4][4] = {};

  for (int K0 = 0; K0 < 1024; K0 += 64) {
    __syncthreads();
#pragma unroll
    for (int t = 0; t < 4; ++t) {
      const int row = wave * 32 + t * 8 + rl;
      const int gc = csel ^ (row & 7);
      const char* ga = Ab + ((size_t)(M0 + row) * 1024 + K0) * 2 + gc * 16;
      __builtin_amdgcn_global_load_lds(
          (const __attribute__((address_space(1))) void*)ga,
          (__attribute__((address_space(3))) void*)(As + (wave * 32 + t * 8) * 128 + lane * 16),
          16, 0, 0);
      const char* gb = Bb + ((size_t)(N0 + row) * 1024 + K0) * 2 + gc * 16;
      __builtin_amdgcn_global_load_lds(
          (const __attribute__((address_space(1))) void*)gb,
          (__attribute__((address_space(3))) void*)(Bs + (wave * 32 + t * 8) * 128 + lane * 16),
          16, 0, 0);
    }
    __syncthreads();
#pragma unroll
    for (int kh = 0; kh < 2; ++kh) {
      bf16x8 af[4], bfr[4];
#pragma unroll
      for (int tm = 0; tm < 4; ++tm) {
        const int r = wm * 64 + tm * 16 + mlane;
        af[tm] = *(const bf16x8*)(As + r * 128 + (((kh * 4 + kgrp) ^ (r & 7)) << 4));
      }
#pragma unroll
      for (int tn = 0; tn < 4; ++tn) {
        const int r = wn * 64 + tn * 16 + mlane;
        bfr[tn] = *(const bf16x8*)(Bs + r * 128 + (((kh * 4 + kgrp) ^ (r & 7)) << 4));
      }
#pragma unroll
      for (int tm = 0; tm < 4; ++tm)
#pragma unroll
        for (int tn = 0; tn < 4; ++tn)
          acc[tm][tn] = __builtin_amdgcn_mfma_f32_16x16x32_bf16(af[tm], bfr[tn], acc[tm][tn], 0, 0, 0);
    }
  }

#pragma unroll
  for (int tm = 0; tm < 4; ++tm)
#pragma unroll
    for (int tn = 0; tn < 4; ++tn) {
      f32x4 v = acc[tm][tn];
#pragma unroll
      for (int r = 0; r < 4; ++r) {
        const int grow = M0 + wm * 64 + tm * 16 + (lane >> 4) * 4 + r;
        const int gcol = N0 + wn * 64 + tn * 16 + mlane;
        float val = v[r];
        if (mode == 1 || mode == 2) {
          const float partner = __shfl_xor(val, 1);
          const int l = grow & (L_ - 1);
          const int i = (gcol >> 1) & 31;
          const float c = ct[l * 32 + i], s = st[l * 32 + i];
          val = (gcol & 1) ? (val * c + partner * s) : (val * c - partner * s);
          outB[(size_t)grow * ldc + gcol] = f2b(val);
        } else if (mode == 0) {
          outB[(size_t)grow * ldc + gcol] = f2b(val);
        } else if (mode == 3) {
          const float x = val + bias[gcol];
          outB[(size_t)grow * ldc + gcol] = f2b(x / (1.0f + expf(-x)));
        } else {
          outF[(size_t)grow * ldc + gcol] = val + bias[gcol];
        }
      }
    }
}

// ---------------------------------------------------------------------------
// merged q/k/v/gate GEMMs: grid (256, 4)
// ---------------------------------------------------------------------------
__global__ __launch_bounds__(256) void gemm4_kernel(
    unsigned short* __restrict__ ws, const float* __restrict__ g_b)
{
  __shared__ __align__(16) char As[128 * 128];
  __shared__ __align__(16) char Bs[128 * 128];
  const int z = blockIdx.y, bx = blockIdx.x;
  float* fb = (float*)(ws + OFF_F32);
  const unsigned short *A, *Bt; unsigned short* outB;
  const float *ct = nullptr, *st = nullptr, *bias = nullptr;
  int mode, ldc, M0, N0;
  if (z == 0) {
    A = ws + OFF_XQB; Bt = ws + OFF_WQT; outB = ws + OFF_QB2;
    ct = fb; st = fb + 65536; mode = 1; ldc = D_;
    M0 = (bx & 31) * 128; N0 = (bx >> 5) * 128;
  } else if (z == 1) {
    A = ws + OFF_XKB; Bt = ws + OFF_WKT; outB = ws + OFF_KB2;
    ct = fb + 131072; st = fb + 196608; mode = 2; ldc = D_;
    M0 = (bx & 31) * 128; N0 = (bx >> 5) * 128;
  } else if (z == 2) {
    A = ws + OFF_WVT; Bt = ws + OFF_XVB; outB = ws + OFF_VTG;
    mode = 0; ldc = M_;
    M0 = (bx & 7) * 128; N0 = (bx >> 3) * 128;
  } else {
    A = ws + OFF_XQB; Bt = ws + OFF_GWB; outB = ws + OFF_GATE;
    bias = g_b; mode = 3; ldc = D_;
    M0 = (bx & 31) * 128; N0 = (bx >> 5) * 128;
  }
  gemm_body(A, Bt, nullptr, outB, ct, st, bias, mode, ldc, M0, N0, As, Bs);
}

__global__ __launch_bounds__(256) void gemm_final_kernel(
    unsigned short* __restrict__ ws, const float* __restrict__ out_b,
    float* __restrict__ out)
{
  __shared__ __align__(16) char As[128 * 128];
  __shared__ __align__(16) char Bs[128 * 128];
  gemm_body(ws + OFF_ABUF, ws + OFF_OWB, out, nullptr, nullptr, nullptr,
            out_b, 4, D_, blockIdx.x * 128, blockIdx.y * 128, As, Bs);
}

// ---------------------------------------------------------------------------
// MFMA retention attention + GroupNorm + gate.
// Static complementary-pair schedule: grid 512, bh = id&31, p = id>>5;
// block processes xq = p then xq = 31-p -> exactly 33 s-tile iters/block.
// P round-trip: wave-local (each wave reads only rows it wrote), so a
// s_waitcnt lgkmcnt(0) + compiler memory fence suffices (round-6 race fix
// mechanism preserved at lower cost than a full barrier).
// ---------------------------------------------------------------------------
#define AQ_OFF 0
#define AK_OFF 8192
#define AV_OFF 16384
#define AP_OFF 24576

__global__ __launch_bounds__(256) void attn_mfma_kernel(
    const unsigned short* __restrict__ qg, const unsigned short* __restrict__ kg,
    const unsigned short* __restrict__ vtg, const unsigned short* __restrict__ gate,
    unsigned short* __restrict__ Abuf)
{
  __shared__ __align__(16) char smem[32768];
  const int tid = threadIdx.x, wave = tid >> 6, lane = tid & 63;
  const int mlane = lane & 15, kgrp = lane >> 4;
  const int rl = lane >> 3, csel = lane & 7;

  const int id = blockIdx.x;
  const int bh = id & 31, p = id >> 5;
  const int b = bh >> 4, h = bh & 15;

  const float lo   = -3.4657359027997265f;
  const float step = -0.1848392481493187f;
  const float gamma = 1.0f - expf(lo + (float)h * step);
  const float lg2g  = log2f(gamma);
  const float g1    = exp2f(-lg2g);
  const float gmr[4] = {1.0f, g1, g1 * g1, g1 * g1 * g1};

#pragma unroll 1
  for (int half = 0; half < 2; ++half) {
    const int xq = half ? (31 - p) : p;
    const int l0 = xq * 64;

    __syncthreads();
    // ---- stage Q (64 x 64 bf16, swizzled) ----
#pragma unroll
    for (int t = 0; t < 2; ++t) {
      const int row = 16 * wave + 8 * t + rl;
      const char* g = (const char*)(qg + (size_t)(b * L_ + l0 + row) * D_ + h * HD_ + ((csel ^ (row & 7)) << 3));
      __builtin_amdgcn_global_load_lds(
          (const __attribute__((address_space(1))) void*)g,
          (__attribute__((address_space(3))) void*)(smem + AQ_OFF + (16 * wave + 8 * t) * 128 + lane * 16),
          16, 0, 0);
    }
    __syncthreads();

    bf16x8 qa[2];
    {
      const int row = 16 * wave + mlane;
#pragma unroll
      for (int kk = 0; kk < 2; ++kk)
        qa[kk] = *(const bf16x8*)(smem + AQ_OFF + row * 128 + (((4 * kk + kgrp) ^ (row & 7)) << 4));
    }
    const float rqm = exp2f((float)(l0 + 16 * wave + mlane) * lg2g);

    f32x4 racc[4] = {};

    for (int it = 0; it <= xq; ++it) {
      const int s0 = it * 64;
      __syncthreads();
#pragma unroll
      for (int t = 0; t < 2; ++t) {
        const int row = 16 * wave + 8 * t + rl;
        const char* gk = (const char*)(kg + (size_t)(b * L_ + s0 + row) * D_ + h * HD_ + ((csel ^ (row & 7)) << 3));
        __builtin_amdgcn_global_load_lds(
            (const __attribute__((address_space(1))) void*)gk,
            (__attribute__((address_space(3))) void*)(smem + AK_OFF + (16 * wave + 8 * t) * 128 + lane * 16),
            16, 0, 0);
        const char* gv = (const char*)(vtg + (size_t)(h * HD_ + row) * M_ + b * L_ + s0 + ((csel ^ (row & 7)) << 3));
        __builtin_amdgcn_global_load_lds(
            (const __attribute__((address_space(1))) void*)gv,
            (__attribute__((address_space(3))) void*)(smem + AV_OFF + (16 * wave + 8 * t) * 128 + lane * 16),
            16, 0, 0);
      }
      __syncthreads();

      bf16x8 kb[4][2], vb[4][2];
#pragma unroll
      for (int tn = 0; tn < 4; ++tn)
#pragma unroll
        for (int kk = 0; kk < 2; ++kk) {
          const int row = 16 * tn + mlane;
          const int sw = ((4 * kk + kgrp) ^ (row & 7)) << 4;
          kb[tn][kk] = *(const bf16x8*)(smem + AK_OFF + row * 128 + sw);
          vb[tn][kk] = *(const bf16x8*)(smem + AV_OFF + row * 128 + sw);
        }
      float csb[4];
#pragma unroll
      for (int tn = 0; tn < 4; ++tn)
        csb[tn] = exp2f(-(float)(s0 + 16 * tn + 4 * kgrp) * lg2g);

      // S^T = K . Q^T : lane col n = l0+16w+mlane, rows s = s0+16tn+4kgrp+r
      f32x4 sf[4];
#pragma unroll
      for (int tn = 0; tn < 4; ++tn) {
        f32x4 z = {};
        z = __builtin_amdgcn_mfma_f32_16x16x32_bf16(kb[tn][0], qa[0], z, 0, 0, 0);
        sf[tn] = __builtin_amdgcn_mfma_f32_16x16x32_bf16(kb[tn][1], qa[1], z, 0, 0, 0);
      }
      const int nrow = l0 + 16 * wave + mlane;
      const bool needMask = (it == xq);
      const int prow = 16 * wave + mlane;
#pragma unroll
      for (int tn = 0; tn < 4; ++tn) {
        const float wbase = rqm * csb[tn];
        const int sbase = s0 + 16 * tn + 4 * kgrp;
        float vv[4];
#pragma unroll
        for (int r = 0; r < 4; ++r) {
          float w = wbase * gmr[r];
          if (needMask) w = (nrow - (sbase + r) >= 0) ? w : 0.0f;
          vv[r] = sf[tn][r] * w;
        }
        s16x4 pk;
        pk[0] = (short)f2b(vv[0]); pk[1] = (short)f2b(vv[1]);
        pk[2] = (short)f2b(vv[2]); pk[3] = (short)f2b(vv[3]);
        *(s16x4*)(smem + AP_OFF + prow * 128 +
                  (((2 * tn + (kgrp >> 1)) ^ (prow & 7)) << 4) + ((kgrp & 1) << 3)) = pk;
      }
      // wave-local fence: drain LDS writes + forbid compiler from hoisting
      // the P-frag reads above the writes (each wave reads only its own rows)
      asm volatile("s_waitcnt lgkmcnt(0)" ::: "memory");
      bf16x8 pa[2];
#pragma unroll
      for (int kk = 0; kk < 2; ++kk) {
        const int row = 16 * wave + mlane;
        pa[kk] = *(const bf16x8*)(smem + AP_OFF + row * 128 + (((4 * kk + kgrp) ^ (row & 7)) << 4));
      }
#pragma unroll
      for (int tn = 0; tn < 4; ++tn) {
        racc[tn] = __builtin_amdgcn_mfma_f32_16x16x32_bf16(pa[0], vb[tn][0], racc[tn], 0, 0, 0);
        racc[tn] = __builtin_amdgcn_mfma_f32_16x16x32_bf16(pa[1], vb[tn][1], racc[tn], 0, 0, 0);
      }
    }

    // ---- GroupNorm + gate, bf16 out ----
#pragma unroll
    for (int r = 0; r < 4; ++r) {
      float vv[4], sm = 0.0f, sq = 0.0f;
#pragma unroll
      for (int tn = 0; tn < 4; ++tn) {
        vv[tn] = racc[tn][r];
        sm += vv[tn]; sq += vv[tn] * vv[tn];
      }
#pragma unroll
      for (int off = 1; off < 16; off <<= 1) {
        sm += __shfl_xor(sm, off);
        sq += __shfl_xor(sq, off);
      }
      const float mu = sm * (1.0f / 64.0f);
      float var = sq * (1.0f / 64.0f) - mu * mu;
      var = fmaxf(var, 0.0f);
      const float inv = rsqrtf(var + 1e-5f);
      const int row = l0 + 16 * wave + kgrp * 4 + r;
      const size_t base = (size_t)(b * L_ + row) * D_ + h * HD_;
#pragma unroll
      for (int tn = 0; tn < 4; ++tn) {
        const int c = 16 * tn + mlane;
        const float g = b2f(gate[base + c]);
        Abuf[base + c] = f2b((vv[tn] - mu) * inv * g);
      }
    }
  }
}

// ---------------------------------------------------------------------------
extern "C" void kernel_launch(void* const* d_in, const int* in_sizes, int n_in,
                              void* d_out, int out_size, void* d_ws, size_t ws_size,
                              hipStream_t stream)
{
  const float* query = (const float*)d_in[0];
  const float* key   = (const float*)d_in[1];
  const float* value = (const float*)d_in[2];
  const float* W_Q   = (const float*)d_in[3];
  const float* W_K   = (const float*)d_in[4];
  const float* W_V   = (const float*)d_in[5];
  const float* g_b   = (const float*)d_in[7];
  const float* out_b = (const float*)d_in[9];
  float* out = (float*)d_out;

  unsigned short* ws = (unsigned short*)d_ws;

  prep_kernel<<<17664, 256, 0, stream>>>(query, key, value,
                                         (const float*)d_in[6],
                                         (const float*)d_in[8],
                                         W_Q, W_K, W_V, ws);

  gemm4_kernel<<<dim3(256, 4), 256, 0, stream>>>(ws, g_b);

  attn_mfma_kernel<<<512, 256, 0, stream>>>(ws + OFF_QB2, ws + OFF_KB2,
                                            ws + OFF_VTG, ws + OFF_GATE,
                                            ws + OFF_ABUF);

  gemm_final_kernel<<<dim3(32, 8), 256, 0, stream>>>(ws, out_b, out);
}

// Round 9
// 235.158 us; speedup vs baseline: 1.0738x; 1.0738x over previous
//
#include <hip/hip_runtime.h>
#include <cstdint>

#define B_  2
#define L_  2048
#define D_  1024
#define H_  16
#define HD_ 64
#define M_  (B_*L_)   // 4096

#define MD  4194304u   // M_*D_
#define DD  1048576u   // D_*D_

// workspace layout (element offsets, unsigned short)
#define OFF_XQB  0u
#define OFF_XKB  (MD)
#define OFF_XVB  (2u*MD)
#define OFF_WQT  (3u*MD)
#define OFF_WKT  (3u*MD + DD)
#define OFF_WVT  (3u*MD + 2u*DD)
#define OFF_GWB  (3u*MD + 3u*DD)
#define OFF_OWB  (3u*MD + 4u*DD)
#define OFF_GATE (3u*MD + 5u*DD)
#define OFF_QB2  (OFF_GATE + MD)
#define OFF_KB2  (OFF_QB2 + MD)
#define OFF_VTG  (OFF_KB2 + MD)
#define OFF_ABUF (OFF_VTG + MD)
#define OFF_F32  (OFF_ABUF + MD)   // float region: ctq|stq|ctk|stk (65536 each)

typedef __attribute__((ext_vector_type(8))) short bf16x8;
typedef __attribute__((ext_vector_type(4))) short s16x4;
typedef __attribute__((ext_vector_type(4))) float f32x4;

__device__ __forceinline__ unsigned short f2b(float x){
  union { float f; unsigned u; } a; a.f = x;
  unsigned r = a.u + 0x7FFFu + ((a.u >> 16) & 1u);
  return (unsigned short)(r >> 16);
}
__device__ __forceinline__ float b2f(unsigned short u){
  union { unsigned u; float f; } a; a.u = ((unsigned)u) << 16; return a.f;
}

// ---------------------------------------------------------------------------
// merged prep: [0,14336) cast; [14336,17408) weight transpose; [17408,17664) xpos
// ---------------------------------------------------------------------------
__global__ __launch_bounds__(256) void prep_kernel(
    const float* __restrict__ q, const float* __restrict__ k,
    const float* __restrict__ v, const float* __restrict__ gw,
    const float* __restrict__ ow, const float* __restrict__ WQ,
    const float* __restrict__ WK, const float* __restrict__ WV,
    unsigned short* __restrict__ ws)
{
  __shared__ float t[32][33];
  const int bx = blockIdx.x, tid = threadIdx.x;
  if (bx < 14336) {
    size_t i = ((size_t)bx * 256 + tid) * 4;
    const float* src; unsigned short* dst;
    if (i < MD)            { src = q  + i;              dst = ws + OFF_XQB + i; }
    else if (i < 2u*MD)    { src = k  + (i - MD);       dst = ws + OFF_XKB + (i - MD); }
    else if (i < 3u*MD)    { src = v  + (i - 2u*MD);    dst = ws + OFF_XVB + (i - 2u*MD); }
    else if (i < 3u*MD+DD) { src = gw + (i - 3u*MD);    dst = ws + OFF_GWB + (i - 3u*MD); }
    else                   { src = ow + (i - 3u*MD-DD); dst = ws + OFF_OWB + (i - 3u*MD - DD); }
    float4 vv = *(const float4*)src;
    ushort4 o; o.x = f2b(vv.x); o.y = f2b(vv.y); o.z = f2b(vv.z); o.w = f2b(vv.w);
    *(ushort4*)dst = o;
  } else if (bx < 17408) {
    const int tb = bx - 14336;
    const int w = tb >> 10;
    const int tb2 = tb & 1023;
    const int h = tb2 >> 6, tt = tb2 & 63;
    const int e0 = (tt & 1) * 32, d0 = (tt >> 1) * 32;
    const float* in = (w == 0) ? WQ : (w == 1) ? WK : WV;
    unsigned short* out = ws + ((w == 0) ? OFF_WQT : (w == 1) ? OFF_WKT : OFF_WVT);
    const int x = tid & 31, y0 = tid >> 5;
    for (int yy = y0; yy < 32; yy += 8)
      t[yy][x] = in[((size_t)h * D_ + d0 + yy) * HD_ + e0 + x];
    __syncthreads();
    for (int yy = y0; yy < 32; yy += 8)
      out[((size_t)h * HD_ + e0 + yy) * D_ + d0 + x] = f2b(t[x][yy]);
  } else {
    float* fb = (float*)(ws + OFF_F32);
    const int idx = (bx - 17408) * 256 + tid;
    const int l = idx >> 5, i = idx & 31;
    const float base = (2.0f * (float)i + 0.4f * (float)HD_) / (1.4f * (float)HD_);
    const float p = (float)(l - L_ / 2) * (1.0f / 512.0f);
    const float sc = exp2f(p * log2f(base));
    const float invf = exp2f(-(float)i * (13.287712379549449f / 32.0f));
    float s, c; sincosf((float)l * invf, &s, &c);
    fb[          l * 32 + i] = c * sc;
    fb[ 65536 +  l * 32 + i] = s * sc;
    const float is = 1.0f / sc;
    fb[131072 +  l * 32 + i] = c * is;
    fb[196608 +  l * 32 + i] = s * is;
  }
}

// ---------------------------------------------------------------------------
// GEMM body (round-7 config, known-good): 128x64 tile, K=1024, BK=64,
// bf16 MFMA, XOR-chunk swizzle. As 16 KB, Bs 8 KB. acc 4x2.
// modes: 0 plain->bf16; 1/2 xpos->bf16; 3 silu+bias->bf16; 4 +bias->fp32
// ---------------------------------------------------------------------------
__device__ __forceinline__ void gemm_body(
    const unsigned short* __restrict__ A, const unsigned short* __restrict__ Bt,
    float* __restrict__ outF, unsigned short* __restrict__ outB,
    const float* __restrict__ ct, const float* __restrict__ st,
    const float* __restrict__ bias, int mode, int ldc, int M0, int N0,
    char* As, char* Bs)
{
  const int tid = threadIdx.x;
  const int wave = tid >> 6, lane = tid & 63;
  const int wm = wave & 1, wn = wave >> 1;
  const int mlane = lane & 15, kgrp = lane >> 4;
  const int rl = lane >> 3, csel = lane & 7;
  const char* Ab = (const char*)A;
  const char* Bb = (const char*)Bt;

  f32x4 acc[4][2] = {};

  for (int K0 = 0; K0 < 1024; K0 += 64) {
    __syncthreads();
#pragma unroll
    for (int t = 0; t < 4; ++t) {
      const int row = wave * 32 + t * 8 + rl;
      const int gc = csel ^ (row & 7);
      const char* ga = Ab + ((size_t)(M0 + row) * 1024 + K0) * 2 + gc * 16;
      __builtin_amdgcn_global_load_lds(
          (const __attribute__((address_space(1))) void*)ga,
          (__attribute__((address_space(3))) void*)(As + (wave * 32 + t * 8) * 128 + lane * 16),
          16, 0, 0);
    }
#pragma unroll
    for (int t = 0; t < 2; ++t) {
      const int row = wave * 16 + t * 8 + rl;
      const int gc = csel ^ (row & 7);
      const char* gb = Bb + ((size_t)(N0 + row) * 1024 + K0) * 2 + gc * 16;
      __builtin_amdgcn_global_load_lds(
          (const __attribute__((address_space(1))) void*)gb,
          (__attribute__((address_space(3))) void*)(Bs + (wave * 16 + t * 8) * 128 + lane * 16),
          16, 0, 0);
    }
    __syncthreads();
#pragma unroll
    for (int kh = 0; kh < 2; ++kh) {
      bf16x8 af[4], bfr[2];
#pragma unroll
      for (int tm = 0; tm < 4; ++tm) {
        const int r = wm * 64 + tm * 16 + mlane;
        af[tm] = *(const bf16x8*)(As + r * 128 + (((kh * 4 + kgrp) ^ (r & 7)) << 4));
      }
#pragma unroll
      for (int tn = 0; tn < 2; ++tn) {
        const int r = wn * 32 + tn * 16 + mlane;
        bfr[tn] = *(const bf16x8*)(Bs + r * 128 + (((kh * 4 + kgrp) ^ (r & 7)) << 4));
      }
#pragma unroll
      for (int tm = 0; tm < 4; ++tm)
#pragma unroll
        for (int tn = 0; tn < 2; ++tn)
          acc[tm][tn] = __builtin_amdgcn_mfma_f32_16x16x32_bf16(af[tm], bfr[tn], acc[tm][tn], 0, 0, 0);
    }
  }

#pragma unroll
  for (int tm = 0; tm < 4; ++tm)
#pragma unroll
    for (int tn = 0; tn < 2; ++tn) {
      f32x4 v = acc[tm][tn];
#pragma unroll
      for (int r = 0; r < 4; ++r) {
        const int grow = M0 + wm * 64 + tm * 16 + (lane >> 4) * 4 + r;
        const int gcol = N0 + wn * 32 + tn * 16 + mlane;
        float val = v[r];
        if (mode == 1 || mode == 2) {
          const float partner = __shfl_xor(val, 1);
          const int l = grow & (L_ - 1);
          const int i = (gcol >> 1) & 31;
          const float c = ct[l * 32 + i], s = st[l * 32 + i];
          val = (gcol & 1) ? (val * c + partner * s) : (val * c - partner * s);
          outB[(size_t)grow * ldc + gcol] = f2b(val);
        } else if (mode == 0) {
          outB[(size_t)grow * ldc + gcol] = f2b(val);
        } else if (mode == 3) {
          const float x = val + bias[gcol];
          outB[(size_t)grow * ldc + gcol] = f2b(x / (1.0f + expf(-x)));
        } else {
          outF[(size_t)grow * ldc + gcol] = val + bias[gcol];
        }
      }
    }
}

// ---------------------------------------------------------------------------
// merged q/k/v/gate GEMMs: grid (512, 4)
// ---------------------------------------------------------------------------
__global__ __launch_bounds__(256) void gemm4_kernel(
    unsigned short* __restrict__ ws, const float* __restrict__ g_b)
{
  __shared__ __align__(16) char As[128 * 128];
  __shared__ __align__(16) char Bs[64 * 128];
  const int z = blockIdx.y, bx = blockIdx.x;
  float* fb = (float*)(ws + OFF_F32);
  const unsigned short *A, *Bt; unsigned short* outB;
  const float *ct = nullptr, *st = nullptr, *bias = nullptr;
  int mode, ldc, M0, N0;
  if (z == 0) {
    A = ws + OFF_XQB; Bt = ws + OFF_WQT; outB = ws + OFF_QB2;
    ct = fb; st = fb + 65536; mode = 1; ldc = D_;
    M0 = (bx & 31) * 128; N0 = (bx >> 5) * 64;
  } else if (z == 1) {
    A = ws + OFF_XKB; Bt = ws + OFF_WKT; outB = ws + OFF_KB2;
    ct = fb + 131072; st = fb + 196608; mode = 2; ldc = D_;
    M0 = (bx & 31) * 128; N0 = (bx >> 5) * 64;
  } else if (z == 2) {
    A = ws + OFF_WVT; Bt = ws + OFF_XVB; outB = ws + OFF_VTG;
    mode = 0; ldc = M_;
    M0 = (bx & 7) * 128; N0 = (bx >> 3) * 64;
  } else {
    A = ws + OFF_XQB; Bt = ws + OFF_GWB; outB = ws + OFF_GATE;
    bias = g_b; mode = 3; ldc = D_;
    M0 = (bx & 31) * 128; N0 = (bx >> 5) * 64;
  }
  gemm_body(A, Bt, nullptr, outB, ct, st, bias, mode, ldc, M0, N0, As, Bs);
}

__global__ __launch_bounds__(256) void gemm_final_kernel(
    unsigned short* __restrict__ ws, const float* __restrict__ out_b,
    float* __restrict__ out)
{
  __shared__ __align__(16) char As[128 * 128];
  __shared__ __align__(16) char Bs[64 * 128];
  gemm_body(ws + OFF_ABUF, ws + OFF_OWB, out, nullptr, nullptr, nullptr,
            out_b, 4, D_, blockIdx.x * 128, blockIdx.y * 64, As, Bs);
}

// ---------------------------------------------------------------------------
// MFMA retention attention + GroupNorm + gate, s-tile 128.
// Pair schedule: grid 512, bh = id&31, p = id>>5; halves xq = p, 31-p.
// Iters per half: (xq+2)>>1 of 128-wide s-tiles; pair total = 17, uniform.
// LDS: Q 8K (128B rows) | K 16K (128 s-rows x 128B) | V^T 16K (64 e-rows x
// 256B) | P 16K (64 q-rows x 256B) = 56 KB -> 2 blocks/CU.
// 256B rows use 16 chunks with XOR-low3 swizzle -> 2-way bank alias (free).
// P round-trip is wave-local: s_waitcnt lgkmcnt(0) + memory clobber fence.
// ---------------------------------------------------------------------------
#define AQ_OFF 0
#define AK_OFF 8192
#define AV_OFF 24576
#define AP_OFF 40960

__global__ __launch_bounds__(256) void attn_mfma_kernel(
    const unsigned short* __restrict__ qg, const unsigned short* __restrict__ kg,
    const unsigned short* __restrict__ vtg, const unsigned short* __restrict__ gate,
    unsigned short* __restrict__ Abuf)
{
  __shared__ __align__(16) char smem[57344];
  const int tid = threadIdx.x, wave = tid >> 6, lane = tid & 63;
  const int mlane = lane & 15, kgrp = lane >> 4;
  const int rl8 = lane >> 3, cs8 = lane & 7;
  const int rl4 = lane >> 4, cs16 = lane & 15;

  const int id = blockIdx.x;
  const int bh = id & 31, p = id >> 5;
  const int b = bh >> 4, h = bh & 15;

  const float lo   = -3.4657359027997265f;
  const float step = -0.1848392481493187f;
  const float gamma = 1.0f - expf(lo + (float)h * step);
  const float lg2g  = log2f(gamma);
  const float g1    = exp2f(-lg2g);
  const float gmr[4] = {1.0f, g1, g1 * g1, g1 * g1 * g1};

#pragma unroll 1
  for (int half = 0; half < 2; ++half) {
    const int xq = half ? (31 - p) : p;
    const int l0 = xq * 64;

    __syncthreads();
    // ---- stage Q (64 x 64 bf16, 128B rows, swizzled) ----
#pragma unroll
    for (int t = 0; t < 2; ++t) {
      const int row = 16 * wave + 8 * t + rl8;
      const char* g = (const char*)(qg + (size_t)(b * L_ + l0 + row) * D_ + h * HD_ + ((cs8 ^ (row & 7)) << 3));
      __builtin_amdgcn_global_load_lds(
          (const __attribute__((address_space(1))) void*)g,
          (__attribute__((address_space(3))) void*)(smem + AQ_OFF + (16 * wave + 8 * t) * 128 + lane * 16),
          16, 0, 0);
    }
    __syncthreads();

    bf16x8 qa[2];
    {
      const int row = 16 * wave + mlane;
#pragma unroll
      for (int kk = 0; kk < 2; ++kk)
        qa[kk] = *(const bf16x8*)(smem + AQ_OFF + row * 128 + (((4 * kk + kgrp) ^ (row & 7)) << 4));
    }
    const float rqm = exp2f((float)(l0 + 16 * wave + mlane) * lg2g);
    const int nrow = l0 + 16 * wave + mlane;
    const int prow = 16 * wave + mlane;

    f32x4 racc[4] = {};
    const int nst = (xq + 2) >> 1;

    for (int it = 0; it < nst; ++it) {
      const int s0 = it * 128;
      __syncthreads();
      // ---- stage K tile: 128 s-rows x 64 e (128B rows) ----
#pragma unroll
      for (int t = 0; t < 4; ++t) {
        const int row = 32 * wave + 8 * t + rl8;
        const char* gk = (const char*)(kg + (size_t)(b * L_ + s0 + row) * D_ + h * HD_ + ((cs8 ^ (row & 7)) << 3));
        __builtin_amdgcn_global_load_lds(
            (const __attribute__((address_space(1))) void*)gk,
            (__attribute__((address_space(3))) void*)(smem + AK_OFF + (32 * wave + 8 * t) * 128 + lane * 16),
            16, 0, 0);
      }
      // ---- stage V^T tile: 64 e-rows x 128 s (256B rows, 16 chunks) ----
#pragma unroll
      for (int t = 0; t < 4; ++t) {
        const int row = 16 * wave + 4 * t + rl4;     // e index
        const char* gv = (const char*)(vtg + (size_t)(h * HD_ + row) * M_ + b * L_ + s0 + ((cs16 ^ (row & 7)) << 3));
        __builtin_amdgcn_global_load_lds(
            (const __attribute__((address_space(1))) void*)gv,
            (__attribute__((address_space(3))) void*)(smem + AV_OFF + (16 * wave + 4 * t) * 256 + lane * 16),
            16, 0, 0);
      }
      __syncthreads();

      // ---- S^T = K . Q^T over 128 s-rows (8 blocks of 16) ----
      f32x4 sf[8];
#pragma unroll
      for (int tn = 0; tn < 8; ++tn) {
        const int row = 16 * tn + mlane;
        const bf16x8 kb0 = *(const bf16x8*)(smem + AK_OFF + row * 128 + ((kgrp ^ (row & 7)) << 4));
        const bf16x8 kb1 = *(const bf16x8*)(smem + AK_OFF + row * 128 + (((4 + kgrp) ^ (row & 7)) << 4));
        f32x4 z = {};
        z = __builtin_amdgcn_mfma_f32_16x16x32_bf16(kb0, qa[0], z, 0, 0, 0);
        sf[tn] = __builtin_amdgcn_mfma_f32_16x16x32_bf16(kb1, qa[1], z, 0, 0, 0);
      }

      // ---- decay + mask + pack P (bf16) ----
      const bool needMask = (it == nst - 1);
#pragma unroll
      for (int tn = 0; tn < 8; ++tn) {
        const float csb = exp2f(-(float)(s0 + 16 * tn + 4 * kgrp) * lg2g);
        const float wbase = rqm * csb;
        const int sbase = s0 + 16 * tn + 4 * kgrp;
        float vv[4];
#pragma unroll
        for (int r = 0; r < 4; ++r) {
          float w = wbase * gmr[r];
          if (needMask) w = (nrow - (sbase + r) >= 0) ? w : 0.0f;
          vv[r] = sf[tn][r] * w;
        }
        s16x4 pk;
        pk[0] = (short)f2b(vv[0]); pk[1] = (short)f2b(vv[1]);
        pk[2] = (short)f2b(vv[2]); pk[3] = (short)f2b(vv[3]);
        *(s16x4*)(smem + AP_OFF + prow * 256 +
                  (((2 * tn + (kgrp >> 1)) ^ (prow & 7)) << 4) + ((kgrp & 1) << 3)) = pk;
      }
      // wave-local fence: drain LDS writes + block compiler reordering
      asm volatile("s_waitcnt lgkmcnt(0)" ::: "memory");

      // ---- PV: ret += P . V (k = 128 s) ----
      bf16x8 pa[4];
#pragma unroll
      for (int kk = 0; kk < 4; ++kk)
        pa[kk] = *(const bf16x8*)(smem + AP_OFF + prow * 256 + (((4 * kk + kgrp) ^ (prow & 7)) << 4));
#pragma unroll
      for (int te = 0; te < 4; ++te) {
        const int rowE = 16 * te + mlane;
#pragma unroll
        for (int kk = 0; kk < 4; ++kk) {
          const bf16x8 vbf = *(const bf16x8*)(smem + AV_OFF + rowE * 256 + (((4 * kk + kgrp) ^ (rowE & 7)) << 4));
          racc[te] = __builtin_amdgcn_mfma_f32_16x16x32_bf16(pa[kk], vbf, racc[te], 0, 0, 0);
        }
      }
    }

    // ---- GroupNorm + gate, bf16 out ----
#pragma unroll
    for (int r = 0; r < 4; ++r) {
      float vv[4], sm = 0.0f, sq = 0.0f;
#pragma unroll
      for (int tn = 0; tn < 4; ++tn) {
        vv[tn] = racc[tn][r];
        sm += vv[tn]; sq += vv[tn] * vv[tn];
      }
#pragma unroll
      for (int off = 1; off < 16; off <<= 1) {
        sm += __shfl_xor(sm, off);
        sq += __shfl_xor(sq, off);
      }
      const float mu = sm * (1.0f / 64.0f);
      float var = sq * (1.0f / 64.0f) - mu * mu;
      var = fmaxf(var, 0.0f);
      const float inv = rsqrtf(var + 1e-5f);
      const int row = l0 + 16 * wave + kgrp * 4 + r;
      const size_t base = (size_t)(b * L_ + row) * D_ + h * HD_;
#pragma unroll
      for (int tn = 0; tn < 4; ++tn) {
        const int c = 16 * tn + mlane;
        const float g = b2f(gate[base + c]);
        Abuf[base + c] = f2b((vv[tn] - mu) * inv * g);
      }
    }
  }
}

// ---------------------------------------------------------------------------
extern "C" void kernel_launch(void* const* d_in, const int* in_sizes, int n_in,
                              void* d_out, int out_size, void* d_ws, size_t ws_size,
                              hipStream_t stream)
{
  const float* query = (const float*)d_in[0];
  const float* key   = (const float*)d_in[1];
  const float* value = (const float*)d_in[2];
  const float* W_Q   = (const float*)d_in[3];
  const float* W_K   = (const float*)d_in[4];
  const float* W_V   = (const float*)d_in[5];
  const float* g_b   = (const float*)d_in[7];
  const float* out_b = (const float*)d_in[9];
  float* out = (float*)d_out;

  unsigned short* ws = (unsigned short*)d_ws;

  prep_kernel<<<17664, 256, 0, stream>>>(query, key, value,
                                         (const float*)d_in[6],
                                         (const float*)d_in[8],
                                         W_Q, W_K, W_V, ws);

  gemm4_kernel<<<dim3(512, 4), 256, 0, stream>>>(ws, g_b);

  attn_mfma_kernel<<<512, 256, 0, stream>>>(ws + OFF_QB2, ws + OFF_KB2,
                                            ws + OFF_VTG, ws + OFF_GATE,
                                            ws + OFF_ABUF);

  gemm_final_kernel<<<dim3(32, 16), 256, 0, stream>>>(ws, out_b, out);
}